// Round 1
// baseline (1213.059 us; speedup 1.0000x reference)
//
#include <hip/hip_runtime.h>
#include <hip/hip_bf16.h>

typedef __attribute__((ext_vector_type(8))) short s8v;
typedef __attribute__((ext_vector_type(4))) float f4v;

#define NNODES 100000
#define NEDGES 1600000
#define NFEAT 512
#define NHID 128
#define NCLS 64

static __device__ __forceinline__ short f2bf(float f) {
  __hip_bfloat16 h = __float2bfloat16(f);
  return __builtin_bit_cast(short, h);
}

// ---- edge dtype detection: int64 => odd 32-bit words all zero ----
__global__ __launch_bounds__(1024) void detect_k(const int* __restrict__ ei, int* flag) {
  int i = blockIdx.x * blockDim.x + threadIdx.x;
  if (i < 1024 && ei[2 * i + 1] != 0) atomicOr(flag, 1); // flag=1 -> int32 data
}

__global__ __launch_bounds__(256) void hist_k(const int* __restrict__ ei,
                                              const int* __restrict__ flag,
                                              int* __restrict__ cnt) {
  bool is32 = (*flag != 0);
  int stride = gridDim.x * blockDim.x;
  for (int e = blockIdx.x * blockDim.x + threadIdx.x; e < NEDGES; e += stride) {
    int d = is32 ? ei[NEDGES + e] : ei[2 * NEDGES + 2 * e];
    atomicAdd(&cnt[d], 1);
  }
}

__global__ __launch_bounds__(1024) void scan_k(const int* __restrict__ cnt, int* __restrict__ rs) {
  __shared__ int sm[1024];
  int t = threadIdx.x;
  const int CH = (NNODES + 1023) / 1024; // 98
  int lo = t * CH;
  int hi = lo + CH; if (hi > NNODES) hi = NNODES;
  int sum = 0;
  for (int v = lo; v < hi; ++v) sum += cnt[v];
  sm[t] = sum;
  __syncthreads();
  for (int off = 1; off < 1024; off <<= 1) {
    int val = (t >= off) ? sm[t - off] : 0;
    __syncthreads();
    sm[t] += val;
    __syncthreads();
  }
  int run = (t == 0) ? 0 : sm[t - 1];
  for (int v = lo; v < hi; ++v) { rs[v] = run; run += cnt[v]; }
  if (t == 1023) rs[NNODES] = sm[1023];
}

__global__ __launch_bounds__(256) void dinv_k(const int* __restrict__ cnt, float* __restrict__ dinv) {
  int v = blockIdx.x * blockDim.x + threadIdx.x;
  if (v < NNODES) dinv[v] = rsqrtf((float)(cnt[v] + 1)); // +1 self loop, always > 0
}

__global__ __launch_bounds__(256) void scatter_k(const int* __restrict__ ei,
                                                 const int* __restrict__ flag,
                                                 const int* __restrict__ rs,
                                                 int* __restrict__ cursor,
                                                 int* __restrict__ csrc) {
  bool is32 = (*flag != 0);
  int stride = gridDim.x * blockDim.x;
  for (int e = blockIdx.x * blockDim.x + threadIdx.x; e < NEDGES; e += stride) {
    int s, d;
    if (is32) { s = ei[e];     d = ei[NEDGES + e]; }
    else      { s = ei[2 * e]; d = ei[2 * NEDGES + 2 * e]; }
    int pos = rs[d] + atomicAdd(&cursor[d], 1);
    csrc[pos] = s;
  }
}

// ---- GEMM1: h1[N,128] = relu(x[N,512] @ W1[512,128] + b1), bf16 out ----
__global__ __launch_bounds__(256) void gemm1_k(const float* __restrict__ x,
                                               const float* __restrict__ W1,
                                               const float* __restrict__ b1,
                                               short* __restrict__ h1) {
  __shared__ short xs[64][72];    // row stride 144B = 9*16, 16B aligned
  __shared__ short wls[128][72];  // W1 chunk transposed [col][k]
  int row0 = blockIdx.x * 64;
  int tid = threadIdx.x;
  int lane = tid & 63;
  int wave = tid >> 6;
  int wr = wave * 16;
  f4v acc[8];
#pragma unroll
  for (int i = 0; i < 8; ++i) acc[i] = (f4v){0.f, 0.f, 0.f, 0.f};

  for (int kk = 0; kk < NFEAT; kk += 64) {
    { // stage x chunk [64 rows][64 k] -> bf16
      int r = tid >> 4;
      int c4 = (tid & 15) * 4;
#pragma unroll
      for (int rr = 0; rr < 4; ++rr) {
        int row = rr * 16 + r;
        int grow = row0 + row;
        float4 v = {0.f, 0.f, 0.f, 0.f};
        if (grow < NNODES)
          v = *reinterpret_cast<const float4*>(&x[(size_t)grow * NFEAT + kk + c4]);
        xs[row][c4 + 0] = f2bf(v.x);
        xs[row][c4 + 1] = f2bf(v.y);
        xs[row][c4 + 2] = f2bf(v.z);
        xs[row][c4 + 3] = f2bf(v.w);
      }
    }
    { // stage W1 chunk transposed
      int kr = tid >> 5;        // 0..7
      int c4 = (tid & 31) * 4;  // 0..124
#pragma unroll
      for (int pp = 0; pp < 8; ++pp) {
        int k = pp * 8 + kr;    // 0..63
        float4 v = *reinterpret_cast<const float4*>(&W1[(size_t)(kk + k) * NHID + c4]);
        wls[c4 + 0][k] = f2bf(v.x);
        wls[c4 + 1][k] = f2bf(v.y);
        wls[c4 + 2][k] = f2bf(v.z);
        wls[c4 + 3][k] = f2bf(v.w);
      }
    }
    __syncthreads();
#pragma unroll
    for (int ks = 0; ks < 2; ++ks) {
      s8v a = *reinterpret_cast<const s8v*>(&xs[wr + (lane & 15)][ks * 32 + (lane >> 4) * 8]);
#pragma unroll
      for (int ct = 0; ct < 8; ++ct) {
        s8v b = *reinterpret_cast<const s8v*>(&wls[ct * 16 + (lane & 15)][ks * 32 + (lane >> 4) * 8]);
        acc[ct] = __builtin_amdgcn_mfma_f32_16x16x32_bf16(a, b, acc[ct], 0, 0, 0);
      }
    }
    __syncthreads();
  }
  int col16 = lane & 15;
  int rgrp = (lane >> 4) * 4;
#pragma unroll
  for (int ct = 0; ct < 8; ++ct) {
    int col = ct * 16 + col16;
    float bias = b1[col];
#pragma unroll
    for (int j = 0; j < 4; ++j) {
      int grow = row0 + wr + rgrp + j;
      if (grow < NNODES) {
        float v = acc[ct][j] + bias;
        v = v > 0.f ? v : 0.f;
        h1[(size_t)grow * NHID + col] = f2bf(v);
      }
    }
  }
}

// ---- GEMM2: h0 = h1 @ W2 + b2 ; x0 = h0 ; g0 = dinv*h0 ----
__global__ __launch_bounds__(256) void gemm2_k(const short* __restrict__ h1,
                                               const float* __restrict__ W2,
                                               const float* __restrict__ b2,
                                               const float* __restrict__ dinv,
                                               float* __restrict__ x0,
                                               float* __restrict__ g0) {
  __shared__ short xs[64][136];  // row stride 272B = 17*16
  __shared__ short wls[64][136]; // W2 transposed [col][k]
  int row0 = blockIdx.x * 64;
  int tid = threadIdx.x;
  int lane = tid & 63;
  int wave = tid >> 6;
  int wr = wave * 16;
  f4v acc[4];
#pragma unroll
  for (int i = 0; i < 4; ++i) acc[i] = (f4v){0.f, 0.f, 0.f, 0.f};

  { // stage h1 tile (already bf16)
    int r = tid >> 4;         // 0..15
    int c8 = (tid & 15) * 8;  // 0..120
#pragma unroll
    for (int rr = 0; rr < 4; ++rr) {
      int row = rr * 16 + r;
      int grow = row0 + row;
      s8v v{};
      if (grow < NNODES) v = *reinterpret_cast<const s8v*>(&h1[(size_t)grow * NHID + c8]);
      *reinterpret_cast<s8v*>(&xs[row][c8]) = v;
    }
  }
  { // stage W2 transposed
    int kr = tid >> 4;        // 0..15
    int c4 = (tid & 15) * 4;  // 0..60
#pragma unroll
    for (int pp = 0; pp < 8; ++pp) {
      int k = pp * 16 + kr;   // 0..127
      float4 v = *reinterpret_cast<const float4*>(&W2[(size_t)k * NCLS + c4]);
      wls[c4 + 0][k] = f2bf(v.x);
      wls[c4 + 1][k] = f2bf(v.y);
      wls[c4 + 2][k] = f2bf(v.z);
      wls[c4 + 3][k] = f2bf(v.w);
    }
  }
  __syncthreads();
#pragma unroll
  for (int ks = 0; ks < 4; ++ks) {
    s8v a = *reinterpret_cast<const s8v*>(&xs[wr + (lane & 15)][ks * 32 + (lane >> 4) * 8]);
#pragma unroll
    for (int ct = 0; ct < 4; ++ct) {
      s8v b = *reinterpret_cast<const s8v*>(&wls[ct * 16 + (lane & 15)][ks * 32 + (lane >> 4) * 8]);
      acc[ct] = __builtin_amdgcn_mfma_f32_16x16x32_bf16(a, b, acc[ct], 0, 0, 0);
    }
  }
  int col16 = lane & 15;
  int rgrp = (lane >> 4) * 4;
#pragma unroll
  for (int ct = 0; ct < 4; ++ct) {
    int col = ct * 16 + col16;
    float bias = b2[col];
#pragma unroll
    for (int j = 0; j < 4; ++j) {
      int grow = row0 + wr + rgrp + j;
      if (grow < NNODES) {
        float h = acc[ct][j] + bias;
        x0[(size_t)grow * NCLS + col] = h;
        g0[(size_t)grow * NCLS + col] = dinv[grow] * h;
      }
    }
  }
}

// ---- propagation step on g = dinv*h; optional fused log_softmax ----
__global__ __launch_bounds__(256) void prop_k(const float* __restrict__ gin,
                                              const float* __restrict__ x0,
                                              const float* __restrict__ dinv,
                                              const int* __restrict__ rs,
                                              const int* __restrict__ csrc,
                                              float* __restrict__ gout,
                                              int last) {
  int node = blockIdx.x * 4 + (threadIdx.x >> 6);
  if (node >= NNODES) return;
  int lane = threadIdx.x & 63;
  float sum = gin[(size_t)node * NCLS + lane]; // self loop
  int b = rs[node], e = rs[node + 1];
  int i = b;
  for (; i + 4 <= e; i += 4) {
    int s0 = csrc[i], s1 = csrc[i + 1], s2 = csrc[i + 2], s3 = csrc[i + 3];
    float v0 = gin[(size_t)s0 * NCLS + lane];
    float v1 = gin[(size_t)s1 * NCLS + lane];
    float v2 = gin[(size_t)s2 * NCLS + lane];
    float v3 = gin[(size_t)s3 * NCLS + lane];
    sum += (v0 + v1) + (v2 + v3);
  }
  for (; i < e; ++i) sum += gin[(size_t)csrc[i] * NCLS + lane];
  float dv = dinv[node];
  float h = 0.9f * (dv * sum) + 0.1f * x0[(size_t)node * NCLS + lane];
  if (!last) {
    gout[(size_t)node * NCLS + lane] = dv * h;
  } else {
    float m = h;
    for (int off = 32; off > 0; off >>= 1) m = fmaxf(m, __shfl_xor(m, off));
    float ex = __expf(h - m);
    float s = ex;
    for (int off = 32; off > 0; off >>= 1) s += __shfl_xor(s, off);
    gout[(size_t)node * NCLS + lane] = (h - m) - __logf(s);
  }
}

extern "C" void kernel_launch(void* const* d_in, const int* in_sizes, int n_in,
                              void* d_out, int out_size, void* d_ws, size_t ws_size,
                              hipStream_t stream) {
  const float* x  = (const float*)d_in[0];
  const int*   ei = (const int*)d_in[1];
  const float* W1 = (const float*)d_in[2];
  const float* b1 = (const float*)d_in[3];
  const float* W2 = (const float*)d_in[4];
  const float* b2 = (const float*)d_in[5];

  char* ws = (char*)d_ws;
  short* h1     = (short*)(ws);              // 25.6 MB; reused as gA after gemm2
  float* x0     = (float*)(ws + 25600000);   // 25.6 MB
  int*   csrc   = (int*)(ws + 51200000);     // 6.4 MB
  int*   cnt    = (int*)(ws + 57600000);     // 400 KB
  int*   rs     = (int*)(ws + 58000000);     // 400.1 KB
  int*   cursor = (int*)(ws + 58400128);     // 400 KB
  float* dinv   = (float*)(ws + 58800128);   // 400 KB
  int*   flag   = (int*)(ws + 59200128);     // 4 B
  float* gA     = (float*)(ws);              // alias of h1 region (exactly N*64*4)
  float* gB     = (float*)d_out;             // d_out doubles as ping-pong buffer

  hipMemsetAsync(ws + 57600000, 0, 1600132, stream); // cnt, rs, cursor, dinv, flag

  detect_k<<<1, 1024, 0, stream>>>(ei, flag);
  hist_k<<<2048, 256, 0, stream>>>(ei, flag, cnt);
  scan_k<<<1, 1024, 0, stream>>>(cnt, rs);
  dinv_k<<<(NNODES + 255) / 256, 256, 0, stream>>>(cnt, dinv);
  scatter_k<<<2048, 256, 0, stream>>>(ei, flag, rs, cursor, csrc);

  gemm1_k<<<(NNODES + 63) / 64, 256, 0, stream>>>(x, W1, b1, h1);
  gemm2_k<<<(NNODES + 63) / 64, 256, 0, stream>>>(h1, W2, b2, dinv, x0, gB);

  // g0 in gB(=d_out); odd iters write gA, even write gB; iter 10 reads gA, writes d_out
  for (int t = 1; t <= 10; ++t) {
    const float* gin = (t & 1) ? gB : gA;
    float* gout      = (t & 1) ? gA : gB;
    prop_k<<<(NNODES + 3) / 4, 256, 0, stream>>>(gin, x0, dinv, rs, csrc, gout, t == 10);
  }
}

// Round 2
// 1145.581 us; speedup vs baseline: 1.0589x; 1.0589x over previous
//
#include <hip/hip_runtime.h>
#include <hip/hip_bf16.h>

typedef __attribute__((ext_vector_type(8))) short s8v;
typedef __attribute__((ext_vector_type(4))) float f4v;

#define NNODES 100000
#define NEDGES 1600000
#define NFEAT 512
#define NHID 128
#define NCLS 64

static __device__ __forceinline__ short f2bf(float f) {
  __hip_bfloat16 h = __float2bfloat16(f);
  return __builtin_bit_cast(short, h);
}
static __device__ __forceinline__ float bf2f(unsigned short u) {
  unsigned int i = ((unsigned int)u) << 16;
  return __builtin_bit_cast(float, i);
}

// ---- edge dtype detection: int64 => odd 32-bit words all zero ----
__global__ __launch_bounds__(1024) void detect_k(const int* __restrict__ ei, int* flag) {
  int i = blockIdx.x * blockDim.x + threadIdx.x;
  if (i < 1024 && ei[2 * i + 1] != 0) atomicOr(flag, 1); // flag=1 -> int32 data
}

__global__ __launch_bounds__(256) void hist_k(const int* __restrict__ ei,
                                              const int* __restrict__ flag,
                                              int* __restrict__ cnt) {
  bool is32 = (*flag != 0);
  int stride = gridDim.x * blockDim.x;
  for (int e = blockIdx.x * blockDim.x + threadIdx.x; e < NEDGES; e += stride) {
    int d = is32 ? ei[NEDGES + e] : ei[2 * NEDGES + 2 * e];
    atomicAdd(&cnt[d], 1);
  }
}

__global__ __launch_bounds__(1024) void scan_k(const int* __restrict__ cnt, int* __restrict__ rs) {
  __shared__ int sm[1024];
  int t = threadIdx.x;
  const int CH = (NNODES + 1023) / 1024; // 98
  int lo = t * CH;
  int hi = lo + CH; if (hi > NNODES) hi = NNODES;
  int sum = 0;
  for (int v = lo; v < hi; ++v) sum += cnt[v];
  sm[t] = sum;
  __syncthreads();
  for (int off = 1; off < 1024; off <<= 1) {
    int val = (t >= off) ? sm[t - off] : 0;
    __syncthreads();
    sm[t] += val;
    __syncthreads();
  }
  int run = (t == 0) ? 0 : sm[t - 1];
  for (int v = lo; v < hi; ++v) { rs[v] = run; run += cnt[v]; }
  if (t == 1023) rs[NNODES] = sm[1023];
}

__global__ __launch_bounds__(256) void dinv_k(const int* __restrict__ cnt, float* __restrict__ dinv) {
  int v = blockIdx.x * blockDim.x + threadIdx.x;
  if (v < NNODES) dinv[v] = rsqrtf((float)(cnt[v] + 1)); // +1 self loop, always > 0
}

__global__ __launch_bounds__(256) void scatter_k(const int* __restrict__ ei,
                                                 const int* __restrict__ flag,
                                                 const int* __restrict__ rs,
                                                 int* __restrict__ cursor,
                                                 int* __restrict__ csrc) {
  bool is32 = (*flag != 0);
  int stride = gridDim.x * blockDim.x;
  for (int e = blockIdx.x * blockDim.x + threadIdx.x; e < NEDGES; e += stride) {
    int s, d;
    if (is32) { s = ei[e];     d = ei[NEDGES + e]; }
    else      { s = ei[2 * e]; d = ei[2 * NEDGES + 2 * e]; }
    int pos = rs[d] + atomicAdd(&cursor[d], 1);
    csrc[pos] = s;
  }
}

// ---- weight transpose+convert: W1[512][128] f32 -> W1t[128][512] bf16 ----
__global__ __launch_bounds__(256) void w1t_k(const float* __restrict__ W1, short* __restrict__ W1t) {
  int i = blockIdx.x * 256 + threadIdx.x;
  if (i < NFEAT * NHID) {
    int k = i >> 7, c = i & 127;
    W1t[(size_t)c * NFEAT + k] = f2bf(W1[i]);
  }
}
// W2[128][64] f32 -> W2t[64][128] bf16
__global__ __launch_bounds__(256) void w2t_k(const float* __restrict__ W2, short* __restrict__ W2t) {
  int i = blockIdx.x * 256 + threadIdx.x;
  if (i < NHID * NCLS) {
    int k = i >> 6, c = i & 63;
    W2t[(size_t)c * NHID + k] = f2bf(W2[i]);
  }
}

// ---- GEMM1: h1[N,128] = relu(x[N,512] @ W1 + b1), bf16 out. LDS-free. ----
// A-frag: lane holds A[row=lane&15][k=(lane>>4)*8+j]; B-frag: B[col=lane&15][k];
// D: col=lane&15, row=(lane>>4)*4+j  (convention verified by round-0 pass)
__global__ __launch_bounds__(256) void gemm1_k(const float* __restrict__ x,
                                               const short* __restrict__ W1t,
                                               const float* __restrict__ b1,
                                               short* __restrict__ h1) {
  int tid = threadIdx.x, lane = tid & 63, wave = tid >> 6;
  int rbase = blockIdx.x * 64 + wave * 16;
  int arow = rbase + (lane & 15);
  int crow = arow < NNODES ? arow : NNODES - 1;
  int q = lane >> 4;
  const float* xr = x + (size_t)crow * NFEAT + q * 8;
  const short* bp = W1t + (size_t)(lane & 15) * NFEAT + q * 8;
  f4v acc[8];
#pragma unroll
  for (int i = 0; i < 8; ++i) acc[i] = (f4v){0.f, 0.f, 0.f, 0.f};

#pragma unroll 4
  for (int kk = 0; kk < NFEAT; kk += 32) {
    float4 a0 = *reinterpret_cast<const float4*>(xr + kk);
    float4 a1 = *reinterpret_cast<const float4*>(xr + kk + 4);
    s8v a;
    a[0] = f2bf(a0.x); a[1] = f2bf(a0.y); a[2] = f2bf(a0.z); a[3] = f2bf(a0.w);
    a[4] = f2bf(a1.x); a[5] = f2bf(a1.y); a[6] = f2bf(a1.z); a[7] = f2bf(a1.w);
#pragma unroll
    for (int ct = 0; ct < 8; ++ct) {
      s8v b = *reinterpret_cast<const s8v*>(bp + (size_t)ct * 16 * NFEAT + kk);
      acc[ct] = __builtin_amdgcn_mfma_f32_16x16x32_bf16(a, b, acc[ct], 0, 0, 0);
    }
  }
  int col16 = lane & 15;
  int rg = q * 4;
#pragma unroll
  for (int ct = 0; ct < 8; ++ct) {
    int col = ct * 16 + col16;
    float bias = b1[col];
#pragma unroll
    for (int j = 0; j < 4; ++j) {
      int grow = rbase + rg + j;
      if (grow < NNODES) {
        float v = acc[ct][j] + bias;
        v = v > 0.f ? v : 0.f;
        h1[(size_t)grow * NHID + col] = f2bf(v);
      }
    }
  }
}

// ---- GEMM2: h0 = h1 @ W2 + b2 ; x0bf = bf16(h0) ; g0 = bf16(dinv*h0) ----
__global__ __launch_bounds__(256) void gemm2_k(const short* __restrict__ h1,
                                               const short* __restrict__ W2t,
                                               const float* __restrict__ b2,
                                               const float* __restrict__ dinv,
                                               unsigned short* __restrict__ x0,
                                               unsigned short* __restrict__ g0) {
  int tid = threadIdx.x, lane = tid & 63, wave = tid >> 6;
  int rbase = blockIdx.x * 64 + wave * 16;
  int arow = rbase + (lane & 15);
  int crow = arow < NNODES ? arow : NNODES - 1;
  int q = lane >> 4;
  const short* ar = h1 + (size_t)crow * NHID + q * 8;
  const short* bp = W2t + (size_t)(lane & 15) * NHID + q * 8;
  f4v acc[4];
#pragma unroll
  for (int i = 0; i < 4; ++i) acc[i] = (f4v){0.f, 0.f, 0.f, 0.f};

#pragma unroll
  for (int kk = 0; kk < NHID; kk += 32) {
    s8v a = *reinterpret_cast<const s8v*>(ar + kk);
#pragma unroll
    for (int ct = 0; ct < 4; ++ct) {
      s8v b = *reinterpret_cast<const s8v*>(bp + (size_t)ct * 16 * NHID + kk);
      acc[ct] = __builtin_amdgcn_mfma_f32_16x16x32_bf16(a, b, acc[ct], 0, 0, 0);
    }
  }
  int col16 = lane & 15;
  int rg = q * 4;
#pragma unroll
  for (int ct = 0; ct < 4; ++ct) {
    int col = ct * 16 + col16;
    float bias = b2[col];
#pragma unroll
    for (int j = 0; j < 4; ++j) {
      int grow = rbase + rg + j;
      if (grow < NNODES) {
        float h = acc[ct][j] + bias;
        x0[(size_t)grow * NCLS + col] = (unsigned short)f2bf(h);
        g0[(size_t)grow * NCLS + col] = (unsigned short)f2bf(dinv[grow] * h);
      }
    }
  }
}

// ---- propagation on g = dinv*h (bf16 state, f32 accumulate) ----
__global__ __launch_bounds__(256) void prop_k(const unsigned short* __restrict__ gin,
                                              const unsigned short* __restrict__ x0,
                                              const float* __restrict__ dinv,
                                              const int* __restrict__ rs,
                                              const int* __restrict__ csrc,
                                              unsigned short* __restrict__ gout,
                                              float* __restrict__ out,
                                              int last) {
  int node = blockIdx.x * 4 + (threadIdx.x >> 6);
  if (node >= NNODES) return;
  int lane = threadIdx.x & 63;
  float sum = bf2f(gin[(size_t)node * NCLS + lane]); // self loop
  int b = rs[node], e = rs[node + 1];
  int i = b;
  for (; i + 4 <= e; i += 4) {
    int s0 = csrc[i], s1 = csrc[i + 1], s2 = csrc[i + 2], s3 = csrc[i + 3];
    float v0 = bf2f(gin[(size_t)s0 * NCLS + lane]);
    float v1 = bf2f(gin[(size_t)s1 * NCLS + lane]);
    float v2 = bf2f(gin[(size_t)s2 * NCLS + lane]);
    float v3 = bf2f(gin[(size_t)s3 * NCLS + lane]);
    sum += (v0 + v1) + (v2 + v3);
  }
  for (; i < e; ++i) sum += bf2f(gin[(size_t)csrc[i] * NCLS + lane]);
  float dv = dinv[node];
  float h = 0.9f * (dv * sum) + 0.1f * bf2f(x0[(size_t)node * NCLS + lane]);
  if (!last) {
    gout[(size_t)node * NCLS + lane] = (unsigned short)f2bf(dv * h);
  } else {
    float m = h;
    for (int off = 32; off > 0; off >>= 1) m = fmaxf(m, __shfl_xor(m, off));
    float ex = __expf(h - m);
    float s = ex;
    for (int off = 32; off > 0; off >>= 1) s += __shfl_xor(s, off);
    out[(size_t)node * NCLS + lane] = (h - m) - __logf(s);
  }
}

extern "C" void kernel_launch(void* const* d_in, const int* in_sizes, int n_in,
                              void* d_out, int out_size, void* d_ws, size_t ws_size,
                              hipStream_t stream) {
  const float* x  = (const float*)d_in[0];
  const int*   ei = (const int*)d_in[1];
  const float* W1 = (const float*)d_in[2];
  const float* b1 = (const float*)d_in[3];
  const float* W2 = (const float*)d_in[4];
  const float* b2 = (const float*)d_in[5];

  char* ws = (char*)d_ws;
  // h1 parked in d_out (25.6 MB), freed before the final prop writes d_out.
  short*          h1     = (short*)d_out;
  unsigned short* x0bf   = (unsigned short*)(ws);               // 12.8 MB
  unsigned short* gA     = (unsigned short*)(ws + 12800000);    // 12.8 MB
  unsigned short* gB     = (unsigned short*)(ws + 25600000);    // 12.8 MB
  int*            csrc   = (int*)(ws + 38400000);               // 6.4 MB
  int*            cnt    = (int*)(ws + 44800000);               // 400 KB
  int*            rs     = (int*)(ws + 45200000);               // 400.004 KB
  int*            cursor = (int*)(ws + 45600128);               // 400 KB
  float*          dinv   = (float*)(ws + 46000128);             // 400 KB
  short*          W1t    = (short*)(ws + 46400128);             // 131072 B
  short*          W2t    = (short*)(ws + 46531200);             // 16384 B
  int*            flag   = (int*)(ws + 46547584);               // 4 B

  hipMemsetAsync(ws + 44800000, 0, 1200128, stream); // cnt + rs + cursor
  hipMemsetAsync(ws + 46547584, 0, 4, stream);       // flag

  detect_k<<<1, 1024, 0, stream>>>(ei, flag);
  hist_k<<<2048, 256, 0, stream>>>(ei, flag, cnt);
  scan_k<<<1, 1024, 0, stream>>>(cnt, rs);
  dinv_k<<<(NNODES + 255) / 256, 256, 0, stream>>>(cnt, dinv);
  scatter_k<<<2048, 256, 0, stream>>>(ei, flag, rs, cursor, csrc);

  w1t_k<<<(NFEAT * NHID + 255) / 256, 256, 0, stream>>>(W1, W1t);
  w2t_k<<<(NHID * NCLS + 255) / 256, 256, 0, stream>>>(W2, W2t);

  gemm1_k<<<(NNODES + 63) / 64, 256, 0, stream>>>(x, W1t, b1, h1);
  gemm2_k<<<(NNODES + 63) / 64, 256, 0, stream>>>((const short*)h1, W2t, b2, dinv, x0bf, gB);

  // g0 in gB; odd t writes gA, even t writes gB; t=10 reads gA, writes d_out (f32)
  for (int t = 1; t <= 10; ++t) {
    const unsigned short* gin = (t & 1) ? gB : gA;
    unsigned short* gout      = (t & 1) ? gA : gB;
    prop_k<<<(NNODES + 3) / 4, 256, 0, stream>>>(gin, x0bf, dinv, rs, csrc, gout,
                                                 (float*)d_out, t == 10);
  }
}

// Round 3
// 811.403 us; speedup vs baseline: 1.4950x; 1.4119x over previous
//
#include <hip/hip_runtime.h>
#include <hip/hip_bf16.h>

typedef __attribute__((ext_vector_type(8))) short s8v;
typedef __attribute__((ext_vector_type(4))) float f4v;

#define NNODES 100000
#define NEDGES 1600000
#define NFEAT 512
#define NHID 128
#define NCLS 64

static __device__ __forceinline__ short f2bf(float f) {
  __hip_bfloat16 h = __float2bfloat16(f);
  return __builtin_bit_cast(short, h);
}
static __device__ __forceinline__ float bflo(unsigned int u) {
  return __builtin_bit_cast(float, u << 16);
}
static __device__ __forceinline__ float bfhi(unsigned int u) {
  return __builtin_bit_cast(float, u & 0xFFFF0000u);
}
static __device__ __forceinline__ void glds16(const void* g, void* l) {
  __builtin_amdgcn_global_load_lds(
      (const __attribute__((address_space(1))) unsigned int*)g,
      (__attribute__((address_space(3))) unsigned int*)l, 16, 0, 0);
}

// ---- edge dtype detection: int64 => odd 32-bit words all zero ----
__global__ __launch_bounds__(1024) void detect_k(const int* __restrict__ ei, int* flag) {
  int i = blockIdx.x * blockDim.x + threadIdx.x;
  if (i < 1024 && ei[2 * i + 1] != 0) atomicOr(flag, 1); // flag=1 -> int32 data
}

__global__ __launch_bounds__(256) void hist_k(const int* __restrict__ ei,
                                              const int* __restrict__ flag,
                                              int* __restrict__ cnt) {
  bool is32 = (*flag != 0);
  int stride = gridDim.x * blockDim.x;
  for (int e = blockIdx.x * blockDim.x + threadIdx.x; e < NEDGES; e += stride) {
    int d = is32 ? ei[NEDGES + e] : ei[2 * NEDGES + 2 * e];
    atomicAdd(&cnt[d], 1);
  }
}

__global__ __launch_bounds__(1024) void scan_k(const int* __restrict__ cnt, int* __restrict__ rs) {
  __shared__ int sm[1024];
  int t = threadIdx.x;
  const int CH = (NNODES + 1023) / 1024; // 98
  int lo = t * CH;
  int hi = lo + CH; if (hi > NNODES) hi = NNODES;
  int sum = 0;
  for (int v = lo; v < hi; ++v) sum += cnt[v];
  sm[t] = sum;
  __syncthreads();
  for (int off = 1; off < 1024; off <<= 1) {
    int val = (t >= off) ? sm[t - off] : 0;
    __syncthreads();
    sm[t] += val;
    __syncthreads();
  }
  int run = (t == 0) ? 0 : sm[t - 1];
  for (int v = lo; v < hi; ++v) { rs[v] = run; run += cnt[v]; }
  if (t == 1023) rs[NNODES] = sm[1023];
}

__global__ __launch_bounds__(256) void dinv_k(const int* __restrict__ cnt, float* __restrict__ dinv) {
  int v = blockIdx.x * blockDim.x + threadIdx.x;
  if (v < NNODES) dinv[v] = rsqrtf((float)(cnt[v] + 1)); // +1 self loop, always > 0
}

__global__ __launch_bounds__(256) void scatter_k(const int* __restrict__ ei,
                                                 const int* __restrict__ flag,
                                                 const int* __restrict__ rs,
                                                 int* __restrict__ cursor,
                                                 int* __restrict__ csrc) {
  bool is32 = (*flag != 0);
  int stride = gridDim.x * blockDim.x;
  for (int e = blockIdx.x * blockDim.x + threadIdx.x; e < NEDGES; e += stride) {
    int s, d;
    if (is32) { s = ei[e];     d = ei[NEDGES + e]; }
    else      { s = ei[2 * e]; d = ei[2 * NEDGES + 2 * e]; }
    int pos = rs[d] + atomicAdd(&cursor[d], 1);
    csrc[pos] = s;
  }
}

// ---- weight transpose+convert ----
__global__ __launch_bounds__(256) void w1t_k(const float* __restrict__ W1, short* __restrict__ W1t) {
  int i = blockIdx.x * 256 + threadIdx.x;
  if (i < NFEAT * NHID) {
    int k = i >> 7, c = i & 127;
    W1t[(size_t)c * NFEAT + k] = f2bf(W1[i]);
  }
}
__global__ __launch_bounds__(256) void w2t_k(const float* __restrict__ W2, short* __restrict__ W2t) {
  int i = blockIdx.x * 256 + threadIdx.x;
  if (i < NHID * NCLS) {
    int k = i >> 6, c = i & 63;
    W2t[(size_t)c * NHID + k] = f2bf(W2[i]);
  }
}

// ---- GEMM1: h1[N,128] = relu(x[N,512] @ W1 + b1), bf16 out ----
// x staged f32 via global_load_lds (linear dest, source-swizzled granule^=row&15),
// ds_read_b128 with matching swizzle -> uniform 2 lanes/bank. Double-buffered.
__global__ __launch_bounds__(256) void gemm1_k(const float* __restrict__ x,
                                               const short* __restrict__ W1t,
                                               const float* __restrict__ b1,
                                               short* __restrict__ h1) {
  __shared__ __align__(16) float xs[2][4096]; // 2 x 64 rows x 64 f32 (16KB each)
  int tid = threadIdx.x, lane = tid & 63, wave = tid >> 6;
  int row0 = blockIdx.x * 64;
  int q = lane >> 4;
  int lrow = wave * 16 + (lane & 15);
  const short* bp = W1t + (size_t)(lane & 15) * NFEAT + q * 8;
  f4v acc[8];
#pragma unroll
  for (int i = 0; i < 8; ++i) acc[i] = (f4v){0.f, 0.f, 0.f, 0.f};

  auto stage = [&](int buf, int c) {
#pragma unroll
    for (int i = 0; i < 4; ++i) {
      int row = wave * 16 + i * 4 + (lane >> 4);
      int grow = row0 + row; if (grow >= NNODES) grow = NNODES - 1;
      int gcol = ((lane & 15) ^ (row & 15)) << 2; // float idx within 64-chunk
      const float* src = x + (size_t)grow * NFEAT + c * 64 + gcol;
      glds16(src, &xs[buf][(wave * 16 + i * 4) * 64]);
    }
  };

  stage(0, 0);
  __syncthreads();
  for (int c = 0; c < 8; ++c) {
    int cur = c & 1;
    if (c + 1 < 8) stage(cur ^ 1, c + 1);
    const char* base = (const char*)&xs[cur][0];
#pragma unroll
    for (int s = 0; s < 2; ++s) {
      int ra0 = lrow * 256 + ((s * 128 + q * 32) ^ ((lrow & 15) << 4));
      float4 av0 = *(const float4*)(base + ra0);
      float4 av1 = *(const float4*)(base + (ra0 ^ 16));
      s8v a;
      a[0] = f2bf(av0.x); a[1] = f2bf(av0.y); a[2] = f2bf(av0.z); a[3] = f2bf(av0.w);
      a[4] = f2bf(av1.x); a[5] = f2bf(av1.y); a[6] = f2bf(av1.z); a[7] = f2bf(av1.w);
      const short* bk = bp + c * 64 + s * 32;
#pragma unroll
      for (int ct = 0; ct < 8; ++ct) {
        s8v b = *reinterpret_cast<const s8v*>(bk + (size_t)ct * 16 * NFEAT);
        acc[ct] = __builtin_amdgcn_mfma_f32_16x16x32_bf16(a, b, acc[ct], 0, 0, 0);
      }
    }
    __syncthreads();
  }
  int col16 = lane & 15;
  int rg = q * 4;
  int rbase = row0 + wave * 16;
#pragma unroll
  for (int ct = 0; ct < 8; ++ct) {
    int col = ct * 16 + col16;
    float bias = b1[col];
#pragma unroll
    for (int j = 0; j < 4; ++j) {
      int grow = rbase + rg + j;
      if (grow < NNODES) {
        float v = acc[ct][j] + bias;
        v = v > 0.f ? v : 0.f;
        h1[(size_t)grow * NHID + col] = f2bf(v);
      }
    }
  }
}

// ---- GEMM2: h0 = h1 @ W2 + b2 ; x0bf = bf16(h0) ; g0 = bf16(dinv*h0) ----
__global__ __launch_bounds__(256) void gemm2_k(const short* __restrict__ h1,
                                               const short* __restrict__ W2t,
                                               const float* __restrict__ b2,
                                               const float* __restrict__ dinv,
                                               unsigned short* __restrict__ x0,
                                               unsigned short* __restrict__ g0) {
  __shared__ __align__(16) short hs[8192]; // 64 rows x 128 bf16 (16KB)
  int tid = threadIdx.x, lane = tid & 63, wave = tid >> 6;
  int row0 = blockIdx.x * 64;
  int q = lane >> 4;
  int lrow = wave * 16 + (lane & 15);
  const short* bp = W2t + (size_t)(lane & 15) * NHID + q * 8;
  f4v acc[4];
#pragma unroll
  for (int i = 0; i < 4; ++i) acc[i] = (f4v){0.f, 0.f, 0.f, 0.f};

#pragma unroll
  for (int i = 0; i < 4; ++i) {
    int row = wave * 16 + i * 4 + (lane >> 4);
    int grow = row0 + row; if (grow >= NNODES) grow = NNODES - 1;
    int gcol = ((lane & 15) ^ (row & 15)) * 8; // short idx (granule=8 shorts)
    const short* src = h1 + (size_t)grow * NHID + gcol;
    glds16(src, &hs[(wave * 16 + i * 4) * 128]);
  }
  __syncthreads();
  const char* base = (const char*)hs;
#pragma unroll
  for (int s = 0; s < 4; ++s) {
    int ra = lrow * 256 + (((q + 4 * s) ^ (lrow & 15)) << 4);
    s8v a = *(const s8v*)(base + ra);
    const short* bk = bp + s * 32;
#pragma unroll
    for (int ct = 0; ct < 4; ++ct) {
      s8v b = *reinterpret_cast<const s8v*>(bk + (size_t)ct * 16 * NHID);
      acc[ct] = __builtin_amdgcn_mfma_f32_16x16x32_bf16(a, b, acc[ct], 0, 0, 0);
    }
  }
  int col16 = lane & 15;
  int rg = q * 4;
  int rbase = row0 + wave * 16;
#pragma unroll
  for (int ct = 0; ct < 4; ++ct) {
    int col = ct * 16 + col16;
    float bias = b2[col];
#pragma unroll
    for (int j = 0; j < 4; ++j) {
      int grow = rbase + rg + j;
      if (grow < NNODES) {
        float h = acc[ct][j] + bias;
        x0[(size_t)grow * NCLS + col] = (unsigned short)f2bf(h);
        g0[(size_t)grow * NCLS + col] = (unsigned short)f2bf(dinv[grow] * h);
      }
    }
  }
}

// ---- propagation: 4 nodes/wave, 16 lanes/node, 4 classes/lane (uint2) ----
// gin has a zeroed row at index NNODES used as the null gather target.
__global__ __launch_bounds__(256) void prop_k(const unsigned short* __restrict__ gin,
                                              const unsigned short* __restrict__ x0,
                                              const float* __restrict__ dinv,
                                              const int* __restrict__ rs,
                                              const int* __restrict__ csrc,
                                              unsigned short* __restrict__ gout,
                                              float* __restrict__ out,
                                              int last) {
  int tid = threadIdx.x;
  int lane = tid & 63;
  int r = lane & 15;
  int gbase = lane & 48;
  int node = blockIdx.x * 16 + (tid >> 6) * 4 + (lane >> 4);
  if (node >= NNODES) node = NNODES - 1;
  int b = rs[node];
  int deg = rs[node + 1] - b;

  // self contribution
  uint2 sv = ((const uint2*)(gin + (size_t)node * NCLS))[r];
  float a0 = bflo(sv.x), a1 = bfhi(sv.x), a2 = bflo(sv.y), a3 = bfhi(sv.y);

  // wave-uniform max degree over the 4 groups
  int m = deg;
  m = max(m, __shfl_xor(m, 16));
  m = max(m, __shfl_xor(m, 32));

  int basek = 0;
  for (; basek + 16 <= m; basek += 16) {
    int idx = NNODES;
    if (basek + r < deg) idx = csrc[b + basek + r];
#pragma unroll
    for (int j = 0; j < 16; ++j) {
      int sj = __shfl(idx, gbase + j);
      uint2 v = ((const uint2*)(gin + (size_t)sj * NCLS))[r];
      a0 += bflo(v.x); a1 += bfhi(v.x); a2 += bflo(v.y); a3 += bfhi(v.y);
    }
  }
  if (basek < m) {
    int idx = NNODES;
    if (basek + r < deg) idx = csrc[b + basek + r];
    int rem = m - basek;
    for (int j = 0; j < rem; ++j) {
      int sj = __shfl(idx, gbase + j);
      uint2 v = ((const uint2*)(gin + (size_t)sj * NCLS))[r];
      a0 += bflo(v.x); a1 += bfhi(v.x); a2 += bflo(v.y); a3 += bfhi(v.y);
    }
  }

  float dv = dinv[node];
  uint2 xv = ((const uint2*)(x0 + (size_t)node * NCLS))[r];
  float h0 = 0.9f * (dv * a0) + 0.1f * bflo(xv.x);
  float h1 = 0.9f * (dv * a1) + 0.1f * bfhi(xv.x);
  float h2 = 0.9f * (dv * a2) + 0.1f * bflo(xv.y);
  float h3 = 0.9f * (dv * a3) + 0.1f * bfhi(xv.y);

  if (!last) {
    unsigned int p0 = (unsigned short)f2bf(dv * h0) |
                      ((unsigned int)(unsigned short)f2bf(dv * h1) << 16);
    unsigned int p1 = (unsigned short)f2bf(dv * h2) |
                      ((unsigned int)(unsigned short)f2bf(dv * h3) << 16);
    uint2 o; o.x = p0; o.y = p1;
    ((uint2*)(gout + (size_t)node * NCLS))[r] = o;
  } else {
    float mx = fmaxf(fmaxf(h0, h1), fmaxf(h2, h3));
#pragma unroll
    for (int off = 1; off < 16; off <<= 1) mx = fmaxf(mx, __shfl_xor(mx, off));
    float s = __expf(h0 - mx) + __expf(h1 - mx) + __expf(h2 - mx) + __expf(h3 - mx);
#pragma unroll
    for (int off = 1; off < 16; off <<= 1) s += __shfl_xor(s, off);
    float ls = __logf(s);
    float4 o = {h0 - mx - ls, h1 - mx - ls, h2 - mx - ls, h3 - mx - ls};
    *(float4*)(out + (size_t)node * NCLS + r * 4) = o;
  }
}

extern "C" void kernel_launch(void* const* d_in, const int* in_sizes, int n_in,
                              void* d_out, int out_size, void* d_ws, size_t ws_size,
                              hipStream_t stream) {
  const float* x  = (const float*)d_in[0];
  const int*   ei = (const int*)d_in[1];
  const float* W1 = (const float*)d_in[2];
  const float* b1 = (const float*)d_in[3];
  const float* W2 = (const float*)d_in[4];
  const float* b2 = (const float*)d_in[5];

  char* ws = (char*)d_ws;
  short*          h1     = (short*)d_out;                     // parked in d_out
  unsigned short* x0bf   = (unsigned short*)(ws);             // 12.8 MB
  unsigned short* gA     = (unsigned short*)(ws + 12800000);  // 12.8 MB + 128B zero row
  unsigned short* gB     = (unsigned short*)(ws + 25600128);  // 12.8 MB + 128B zero row
  int*            csrc   = (int*)(ws + 38400256);             // 6.4 MB
  int*            cnt    = (int*)(ws + 44800256);             // 400 KB
  int*            rs     = (int*)(ws + 45200256);             // 400.004 KB
  int*            cursor = (int*)(ws + 45600384);             // 400 KB
  float*          dinv   = (float*)(ws + 46000384);           // 400 KB
  short*          W1t    = (short*)(ws + 46400384);           // 131072 B
  short*          W2t    = (short*)(ws + 46531456);           // 16384 B
  int*            flag   = (int*)(ws + 46547840);             // 4 B

  hipMemsetAsync(ws + 44800256, 0, 1200128, stream); // cnt + rs + cursor
  hipMemsetAsync(ws + 46547840, 0, 4, stream);       // flag
  // zero null-gather row (index NNODES) in both state buffers
  hipMemsetAsync((char*)gA + (size_t)NNODES * NCLS * 2, 0, 128, stream);
  hipMemsetAsync((char*)gB + (size_t)NNODES * NCLS * 2, 0, 128, stream);

  detect_k<<<1, 1024, 0, stream>>>(ei, flag);
  hist_k<<<2048, 256, 0, stream>>>(ei, flag, cnt);
  scan_k<<<1, 1024, 0, stream>>>(cnt, rs);
  dinv_k<<<(NNODES + 255) / 256, 256, 0, stream>>>(cnt, dinv);
  scatter_k<<<2048, 256, 0, stream>>>(ei, flag, rs, cursor, csrc);

  w1t_k<<<(NFEAT * NHID + 255) / 256, 256, 0, stream>>>(W1, W1t);
  w2t_k<<<(NHID * NCLS + 255) / 256, 256, 0, stream>>>(W2, W2t);

  gemm1_k<<<(NNODES + 63) / 64, 256, 0, stream>>>(x, W1t, b1, h1);
  gemm2_k<<<(NNODES + 63) / 64, 256, 0, stream>>>((const short*)h1, W2t, b2, dinv, x0bf, gB);

  // g0 in gB; odd t writes gA, even t writes gB; t=10 reads gA, writes d_out (f32)
  for (int t = 1; t <= 10; ++t) {
    const unsigned short* gin = (t & 1) ? gB : gA;
    unsigned short* gout      = (t & 1) ? gA : gB;
    prop_k<<<(NNODES + 15) / 16, 256, 0, stream>>>(gin, x0bf, dinv, rs, csrc, gout,
                                                   (float*)d_out, t == 10);
  }
}

// Round 4
// 669.075 us; speedup vs baseline: 1.8130x; 1.2127x over previous
//
#include <hip/hip_runtime.h>
#include <hip/hip_bf16.h>

typedef __attribute__((ext_vector_type(8))) short s8v;
typedef __attribute__((ext_vector_type(4))) float f4v;

#define NNODES 100000
#define NEDGES 1600000
#define NFEAT 512
#define NHID 128
#define NCLS 64
#define NB1 391  // ceil(NNODES/256)

static __device__ __forceinline__ short f2bf(float f) {
  __hip_bfloat16 h = __float2bfloat16(f);
  return __builtin_bit_cast(short, h);
}
static __device__ __forceinline__ float bflo(unsigned int u) {
  return __builtin_bit_cast(float, u << 16);
}
static __device__ __forceinline__ float bfhi(unsigned int u) {
  return __builtin_bit_cast(float, u & 0xFFFF0000u);
}
static __device__ __forceinline__ void glds16(const void* g, void* l) {
  __builtin_amdgcn_global_load_lds(
      (const __attribute__((address_space(1))) unsigned int*)g,
      (__attribute__((address_space(3))) unsigned int*)l, 16, 0, 0);
}

// ---- edge dtype detection: int64 => odd 32-bit words all zero ----
__global__ __launch_bounds__(1024) void detect_k(const int* __restrict__ ei, int* flag) {
  int i = blockIdx.x * blockDim.x + threadIdx.x;
  if (i < 1024 && ei[2 * i + 1] != 0) atomicOr(flag, 1); // flag=1 -> int32 data
}

__global__ __launch_bounds__(256) void hist_k(const int* __restrict__ ei,
                                              const int* __restrict__ flag,
                                              int* __restrict__ cnt) {
  bool is32 = (*flag != 0);
  int stride = gridDim.x * blockDim.x;
  for (int e = blockIdx.x * blockDim.x + threadIdx.x; e < NEDGES; e += stride) {
    int d = is32 ? ei[NEDGES + e] : ei[2 * NEDGES + 2 * e];
    atomicAdd(&cnt[d], 1);
  }
}

// ---- hierarchical exclusive scan of cnt -> rs ----
__global__ __launch_bounds__(256) void scan1_k(const int* __restrict__ cnt,
                                               int* __restrict__ rs,
                                               int* __restrict__ bsum) {
  __shared__ int sm[256];
  int t = threadIdx.x;
  int i = blockIdx.x * 256 + t;
  int v = (i < NNODES) ? cnt[i] : 0;
  sm[t] = v;
  __syncthreads();
  for (int off = 1; off < 256; off <<= 1) {
    int val = (t >= off) ? sm[t - off] : 0;
    __syncthreads();
    sm[t] += val;
    __syncthreads();
  }
  if (i < NNODES) rs[i] = sm[t] - v; // exclusive within block
  if (t == 255) bsum[blockIdx.x] = sm[255];
}

__global__ __launch_bounds__(512) void scan2_k(int* __restrict__ bsum, int* __restrict__ rs) {
  __shared__ int sm[512];
  int t = threadIdx.x;
  int v = (t < NB1) ? bsum[t] : 0;
  sm[t] = v;
  __syncthreads();
  for (int off = 1; off < 512; off <<= 1) {
    int val = (t >= off) ? sm[t - off] : 0;
    __syncthreads();
    sm[t] += val;
    __syncthreads();
  }
  if (t < NB1) bsum[t] = sm[t] - v; // exclusive block offsets
  if (t == 511) rs[NNODES] = sm[511];
}

__global__ __launch_bounds__(256) void scan3_k(const int* __restrict__ cnt,
                                               const int* __restrict__ bsum,
                                               int* __restrict__ rs,
                                               float* __restrict__ dinv) {
  int i = blockIdx.x * 256 + threadIdx.x;
  if (i < NNODES) {
    rs[i] += bsum[blockIdx.x];
    dinv[i] = rsqrtf((float)(cnt[i] + 1)); // +1 self loop, always > 0
  }
}

__global__ __launch_bounds__(256) void scatter_k(const int* __restrict__ ei,
                                                 const int* __restrict__ flag,
                                                 const int* __restrict__ rs,
                                                 int* __restrict__ cursor,
                                                 int* __restrict__ csrc) {
  bool is32 = (*flag != 0);
  int stride = gridDim.x * blockDim.x;
  for (int e = blockIdx.x * blockDim.x + threadIdx.x; e < NEDGES; e += stride) {
    int s, d;
    if (is32) { s = ei[e];     d = ei[NEDGES + e]; }
    else      { s = ei[2 * e]; d = ei[2 * NEDGES + 2 * e]; }
    int pos = rs[d] + atomicAdd(&cursor[d], 1);
    csrc[pos] = s;
  }
}

// ---- weight transpose+convert ----
__global__ __launch_bounds__(256) void w1t_k(const float* __restrict__ W1, short* __restrict__ W1t) {
  int i = blockIdx.x * 256 + threadIdx.x;
  if (i < NFEAT * NHID) {
    int k = i >> 7, c = i & 127;
    W1t[(size_t)c * NFEAT + k] = f2bf(W1[i]);
  }
}
__global__ __launch_bounds__(256) void w2t_k(const float* __restrict__ W2, short* __restrict__ W2t) {
  int i = blockIdx.x * 256 + threadIdx.x;
  if (i < NHID * NCLS) {
    int k = i >> 6, c = i & 63;
    W2t[(size_t)c * NHID + k] = f2bf(W2[i]);
  }
}

// ---- GEMM1: h1[N,128] = relu(x[N,512] @ W1 + b1), bf16 out ----
__global__ __launch_bounds__(256) void gemm1_k(const float* __restrict__ x,
                                               const short* __restrict__ W1t,
                                               const float* __restrict__ b1,
                                               short* __restrict__ h1) {
  __shared__ __align__(16) float xs[2][4096]; // 2 x 64 rows x 64 f32 (16KB each)
  int tid = threadIdx.x, lane = tid & 63, wave = tid >> 6;
  int row0 = blockIdx.x * 64;
  int q = lane >> 4;
  int lrow = wave * 16 + (lane & 15);
  const short* bp = W1t + (size_t)(lane & 15) * NFEAT + q * 8;
  f4v acc[8];
#pragma unroll
  for (int i = 0; i < 8; ++i) acc[i] = (f4v){0.f, 0.f, 0.f, 0.f};

  auto stage = [&](int buf, int c) {
#pragma unroll
    for (int i = 0; i < 4; ++i) {
      int row = wave * 16 + i * 4 + (lane >> 4);
      int grow = row0 + row; if (grow >= NNODES) grow = NNODES - 1;
      int gcol = ((lane & 15) ^ (row & 15)) << 2; // float idx within 64-chunk
      const float* src = x + (size_t)grow * NFEAT + c * 64 + gcol;
      glds16(src, &xs[buf][(wave * 16 + i * 4) * 64]);
    }
  };

  stage(0, 0);
  __syncthreads();
  for (int c = 0; c < 8; ++c) {
    int cur = c & 1;
    if (c + 1 < 8) stage(cur ^ 1, c + 1);
    const char* base = (const char*)&xs[cur][0];
#pragma unroll
    for (int s = 0; s < 2; ++s) {
      int ra0 = lrow * 256 + ((s * 128 + q * 32) ^ ((lrow & 15) << 4));
      float4 av0 = *(const float4*)(base + ra0);
      float4 av1 = *(const float4*)(base + (ra0 ^ 16));
      s8v a;
      a[0] = f2bf(av0.x); a[1] = f2bf(av0.y); a[2] = f2bf(av0.z); a[3] = f2bf(av0.w);
      a[4] = f2bf(av1.x); a[5] = f2bf(av1.y); a[6] = f2bf(av1.z); a[7] = f2bf(av1.w);
      const short* bk = bp + c * 64 + s * 32;
#pragma unroll
      for (int ct = 0; ct < 8; ++ct) {
        s8v b = *reinterpret_cast<const s8v*>(bk + (size_t)ct * 16 * NFEAT);
        acc[ct] = __builtin_amdgcn_mfma_f32_16x16x32_bf16(a, b, acc[ct], 0, 0, 0);
      }
    }
    __syncthreads();
  }
  int col16 = lane & 15;
  int rg = q * 4;
  int rbase = row0 + wave * 16;
#pragma unroll
  for (int ct = 0; ct < 8; ++ct) {
    int col = ct * 16 + col16;
    float bias = b1[col];
#pragma unroll
    for (int j = 0; j < 4; ++j) {
      int grow = rbase + rg + j;
      if (grow < NNODES) {
        float v = acc[ct][j] + bias;
        v = v > 0.f ? v : 0.f;
        h1[(size_t)grow * NHID + col] = f2bf(v);
      }
    }
  }
}

// ---- GEMM2: h0 = h1 @ W2 + b2 ; x0bf = bf16(h0) ; g0 = bf16(dinv*h0) ----
__global__ __launch_bounds__(256) void gemm2_k(const short* __restrict__ h1,
                                               const short* __restrict__ W2t,
                                               const float* __restrict__ b2,
                                               const float* __restrict__ dinv,
                                               unsigned short* __restrict__ x0,
                                               unsigned short* __restrict__ g0) {
  __shared__ __align__(16) short hs[8192]; // 64 rows x 128 bf16 (16KB)
  int tid = threadIdx.x, lane = tid & 63, wave = tid >> 6;
  int row0 = blockIdx.x * 64;
  int q = lane >> 4;
  int lrow = wave * 16 + (lane & 15);
  const short* bp = W2t + (size_t)(lane & 15) * NHID + q * 8;
  f4v acc[4];
#pragma unroll
  for (int i = 0; i < 4; ++i) acc[i] = (f4v){0.f, 0.f, 0.f, 0.f};

#pragma unroll
  for (int i = 0; i < 4; ++i) {
    int row = wave * 16 + i * 4 + (lane >> 4);
    int grow = row0 + row; if (grow >= NNODES) grow = NNODES - 1;
    int gcol = ((lane & 15) ^ (row & 15)) * 8; // short idx (granule=8 shorts)
    const short* src = h1 + (size_t)grow * NHID + gcol;
    glds16(src, &hs[(wave * 16 + i * 4) * 128]);
  }
  __syncthreads();
  const char* base = (const char*)hs;
#pragma unroll
  for (int s = 0; s < 4; ++s) {
    int ra = lrow * 256 + (((q + 4 * s) ^ (lrow & 15)) << 4);
    s8v a = *(const s8v*)(base + ra);
    const short* bk = bp + s * 32;
#pragma unroll
    for (int ct = 0; ct < 4; ++ct) {
      s8v b = *reinterpret_cast<const s8v*>(bk + (size_t)ct * 16 * NHID);
      acc[ct] = __builtin_amdgcn_mfma_f32_16x16x32_bf16(a, b, acc[ct], 0, 0, 0);
    }
  }
  int col16 = lane & 15;
  int rg = q * 4;
  int rbase = row0 + wave * 16;
#pragma unroll
  for (int ct = 0; ct < 4; ++ct) {
    int col = ct * 16 + col16;
    float bias = b2[col];
#pragma unroll
    for (int j = 0; j < 4; ++j) {
      int grow = rbase + rg + j;
      if (grow < NNODES) {
        float h = acc[ct][j] + bias;
        x0[(size_t)grow * NCLS + col] = (unsigned short)f2bf(h);
        g0[(size_t)grow * NCLS + col] = (unsigned short)f2bf(dinv[grow] * h);
      }
    }
  }
}

// ---- propagation: 4 nodes/wave, 16 lanes/node, 4 classes/lane (uint2) ----
__global__ __launch_bounds__(256) void prop_k(const unsigned short* __restrict__ gin,
                                              const unsigned short* __restrict__ x0,
                                              const float* __restrict__ dinv,
                                              const int* __restrict__ rs,
                                              const int* __restrict__ csrc,
                                              unsigned short* __restrict__ gout,
                                              float* __restrict__ out,
                                              int last) {
  int tid = threadIdx.x;
  int lane = tid & 63;
  int r = lane & 15;
  int gbase = lane & 48;
  int node = blockIdx.x * 16 + (tid >> 6) * 4 + (lane >> 4);
  if (node >= NNODES) node = NNODES - 1;
  int b = rs[node];
  int deg = rs[node + 1] - b;

  // self contribution
  uint2 sv = ((const uint2*)(gin + (size_t)node * NCLS))[r];
  float a0 = bflo(sv.x), a1 = bfhi(sv.x), a2 = bflo(sv.y), a3 = bfhi(sv.y);

  // wave-uniform max degree over the 4 groups
  int m = deg;
  m = max(m, __shfl_xor(m, 16));
  m = max(m, __shfl_xor(m, 32));

  int basek = 0;
  for (; basek + 16 <= m; basek += 16) {
    int idx = NNODES;
    if (basek + r < deg) idx = csrc[b + basek + r];
#pragma unroll
    for (int j = 0; j < 16; ++j) {
      int sj = __shfl(idx, gbase + j);
      uint2 v = ((const uint2*)(gin + (size_t)sj * NCLS))[r];
      a0 += bflo(v.x); a1 += bfhi(v.x); a2 += bflo(v.y); a3 += bfhi(v.y);
    }
  }
  if (basek < m) {
    int idx = NNODES;
    if (basek + r < deg) idx = csrc[b + basek + r];
    int rem = m - basek;
    for (int j = 0; j < rem; ++j) {
      int sj = __shfl(idx, gbase + j);
      uint2 v = ((const uint2*)(gin + (size_t)sj * NCLS))[r];
      a0 += bflo(v.x); a1 += bfhi(v.x); a2 += bflo(v.y); a3 += bfhi(v.y);
    }
  }

  float dv = dinv[node];
  uint2 xv = ((const uint2*)(x0 + (size_t)node * NCLS))[r];
  float h0 = 0.9f * (dv * a0) + 0.1f * bflo(xv.x);
  float h1 = 0.9f * (dv * a1) + 0.1f * bfhi(xv.x);
  float h2 = 0.9f * (dv * a2) + 0.1f * bflo(xv.y);
  float h3 = 0.9f * (dv * a3) + 0.1f * bfhi(xv.y);

  if (!last) {
    unsigned int p0 = (unsigned short)f2bf(dv * h0) |
                      ((unsigned int)(unsigned short)f2bf(dv * h1) << 16);
    unsigned int p1 = (unsigned short)f2bf(dv * h2) |
                      ((unsigned int)(unsigned short)f2bf(dv * h3) << 16);
    uint2 o; o.x = p0; o.y = p1;
    ((uint2*)(gout + (size_t)node * NCLS))[r] = o;
  } else {
    float mx = fmaxf(fmaxf(h0, h1), fmaxf(h2, h3));
#pragma unroll
    for (int off = 1; off < 16; off <<= 1) mx = fmaxf(mx, __shfl_xor(mx, off));
    float s = __expf(h0 - mx) + __expf(h1 - mx) + __expf(h2 - mx) + __expf(h3 - mx);
#pragma unroll
    for (int off = 1; off < 16; off <<= 1) s += __shfl_xor(s, off);
    float ls = __logf(s);
    float4 o = {h0 - mx - ls, h1 - mx - ls, h2 - mx - ls, h3 - mx - ls};
    *(float4*)(out + (size_t)node * NCLS + r * 4) = o;
  }
}

extern "C" void kernel_launch(void* const* d_in, const int* in_sizes, int n_in,
                              void* d_out, int out_size, void* d_ws, size_t ws_size,
                              hipStream_t stream) {
  const float* x  = (const float*)d_in[0];
  const int*   ei = (const int*)d_in[1];
  const float* W1 = (const float*)d_in[2];
  const float* b1 = (const float*)d_in[3];
  const float* W2 = (const float*)d_in[4];
  const float* b2 = (const float*)d_in[5];

  char* ws = (char*)d_ws;
  short*          h1     = (short*)d_out;                     // parked in d_out
  unsigned short* x0bf   = (unsigned short*)(ws);             // 12.8 MB
  unsigned short* gA     = (unsigned short*)(ws + 12800000);  // 12.8 MB + 128B zero row
  unsigned short* gB     = (unsigned short*)(ws + 25600128);  // 12.8 MB + 128B zero row
  int*            csrc   = (int*)(ws + 38400256);             // 6.4 MB
  int*            cnt    = (int*)(ws + 44800256);             // 400 KB
  int*            rs     = (int*)(ws + 45200256);             // 400.004 KB
  int*            cursor = (int*)(ws + 45600384);             // 400 KB
  float*          dinv   = (float*)(ws + 46000384);           // 400 KB
  short*          W1t    = (short*)(ws + 46400384);           // 131072 B
  short*          W2t    = (short*)(ws + 46531456);           // 16384 B
  int*            flag   = (int*)(ws + 46547840);             // 4 B
  int*            bsum   = (int*)(ws + 46547968);             // 1564 B

  hipMemsetAsync(ws + 44800256, 0, 1200128, stream); // cnt + rs + cursor
  hipMemsetAsync(ws + 46547840, 0, 4, stream);       // flag
  // zero null-gather row (index NNODES) in both state buffers
  hipMemsetAsync((char*)gA + (size_t)NNODES * NCLS * 2, 0, 128, stream);
  hipMemsetAsync((char*)gB + (size_t)NNODES * NCLS * 2, 0, 128, stream);

  detect_k<<<1, 1024, 0, stream>>>(ei, flag);
  hist_k<<<2048, 256, 0, stream>>>(ei, flag, cnt);
  scan1_k<<<NB1, 256, 0, stream>>>(cnt, rs, bsum);
  scan2_k<<<1, 512, 0, stream>>>(bsum, rs);
  scan3_k<<<NB1, 256, 0, stream>>>(cnt, bsum, rs, dinv);
  scatter_k<<<2048, 256, 0, stream>>>(ei, flag, rs, cursor, csrc);

  w1t_k<<<(NFEAT * NHID + 255) / 256, 256, 0, stream>>>(W1, W1t);
  w2t_k<<<(NHID * NCLS + 255) / 256, 256, 0, stream>>>(W2, W2t);

  gemm1_k<<<(NNODES + 63) / 64, 256, 0, stream>>>(x, W1t, b1, h1);
  gemm2_k<<<(NNODES + 63) / 64, 256, 0, stream>>>((const short*)h1, W2t, b2, dinv, x0bf, gB);

  // g0 in gB; odd t writes gA, even t writes gB; t=10 reads gA, writes d_out (f32)
  for (int t = 1; t <= 10; ++t) {
    const unsigned short* gin = (t & 1) ? gB : gA;
    unsigned short* gout      = (t & 1) ? gA : gB;
    prop_k<<<(NNODES + 15) / 16, 256, 0, stream>>>(gin, x0bf, dinv, rs, csrc, gout,
                                                   (float*)d_out, t == 10);
  }
}

// Round 5
// 657.620 us; speedup vs baseline: 1.8446x; 1.0174x over previous
//
#include <hip/hip_runtime.h>
#include <hip/hip_bf16.h>

typedef __attribute__((ext_vector_type(8))) short s8v;
typedef __attribute__((ext_vector_type(4))) float f4v;

#define NNODES 100000
#define NEDGES 1600000
#define NFEAT 512
#define NHID 128
#define NCLS 64
#define NB1 391  // ceil(NNODES/256)

static __device__ __forceinline__ short f2bf(float f) {
  __hip_bfloat16 h = __float2bfloat16(f);
  return __builtin_bit_cast(short, h);
}
static __device__ __forceinline__ float bflo(unsigned int u) {
  return __builtin_bit_cast(float, u << 16);
}
static __device__ __forceinline__ float bfhi(unsigned int u) {
  return __builtin_bit_cast(float, u & 0xFFFF0000u);
}

// ---- edge dtype detection: int64 => odd 32-bit words all zero ----
__global__ __launch_bounds__(1024) void detect_k(const int* __restrict__ ei, int* flag) {
  int i = blockIdx.x * blockDim.x + threadIdx.x;
  if (i < 1024 && ei[2 * i + 1] != 0) atomicOr(flag, 1); // flag=1 -> int32 data
}

__global__ __launch_bounds__(256) void hist_k(const int* __restrict__ ei,
                                              const int* __restrict__ flag,
                                              int* __restrict__ cnt) {
  bool is32 = (*flag != 0);
  int stride = gridDim.x * blockDim.x;
  for (int e = blockIdx.x * blockDim.x + threadIdx.x; e < NEDGES; e += stride) {
    int d = is32 ? ei[NEDGES + e] : ei[2 * NEDGES + 2 * e];
    atomicAdd(&cnt[d], 1);
  }
}

// ---- hierarchical exclusive scan of cnt -> rs ----
__global__ __launch_bounds__(256) void scan1_k(const int* __restrict__ cnt,
                                               int* __restrict__ rs,
                                               int* __restrict__ bsum) {
  __shared__ int sm[256];
  int t = threadIdx.x;
  int i = blockIdx.x * 256 + t;
  int v = (i < NNODES) ? cnt[i] : 0;
  sm[t] = v;
  __syncthreads();
  for (int off = 1; off < 256; off <<= 1) {
    int val = (t >= off) ? sm[t - off] : 0;
    __syncthreads();
    sm[t] += val;
    __syncthreads();
  }
  if (i < NNODES) rs[i] = sm[t] - v; // exclusive within block
  if (t == 255) bsum[blockIdx.x] = sm[255];
}

__global__ __launch_bounds__(512) void scan2_k(int* __restrict__ bsum, int* __restrict__ rs) {
  __shared__ int sm[512];
  int t = threadIdx.x;
  int v = (t < NB1) ? bsum[t] : 0;
  sm[t] = v;
  __syncthreads();
  for (int off = 1; off < 512; off <<= 1) {
    int val = (t >= off) ? sm[t - off] : 0;
    __syncthreads();
    sm[t] += val;
    __syncthreads();
  }
  if (t < NB1) bsum[t] = sm[t] - v; // exclusive block offsets
  if (t == 511) rs[NNODES] = sm[511];
}

__global__ __launch_bounds__(256) void scan3_k(const int* __restrict__ cnt,
                                               const int* __restrict__ bsum,
                                               int* __restrict__ rs,
                                               float* __restrict__ dinv) {
  int i = blockIdx.x * 256 + threadIdx.x;
  if (i < NNODES) {
    rs[i] += bsum[blockIdx.x];
    dinv[i] = rsqrtf((float)(cnt[i] + 1)); // +1 self loop, always > 0
  }
}

__global__ __launch_bounds__(256) void scatter_k(const int* __restrict__ ei,
                                                 const int* __restrict__ flag,
                                                 const int* __restrict__ rs,
                                                 int* __restrict__ cursor,
                                                 int* __restrict__ csrc) {
  bool is32 = (*flag != 0);
  int stride = gridDim.x * blockDim.x;
  for (int e = blockIdx.x * blockDim.x + threadIdx.x; e < NEDGES; e += stride) {
    int s, d;
    if (is32) { s = ei[e];     d = ei[NEDGES + e]; }
    else      { s = ei[2 * e]; d = ei[2 * NEDGES + 2 * e]; }
    int pos = rs[d] + atomicAdd(&cursor[d], 1);
    csrc[pos] = s;
  }
}

// ---- weight transpose+convert ----
__global__ __launch_bounds__(256) void w1t_k(const float* __restrict__ W1, short* __restrict__ W1t) {
  int i = blockIdx.x * 256 + threadIdx.x;
  if (i < NFEAT * NHID) {
    int k = i >> 7, c = i & 127;
    W1t[(size_t)c * NFEAT + k] = f2bf(W1[i]);
  }
}
__global__ __launch_bounds__(256) void w2t_k(const float* __restrict__ W2, short* __restrict__ W2t) {
  int i = blockIdx.x * 256 + threadIdx.x;
  if (i < NHID * NCLS) {
    int k = i >> 6, c = i & 63;
    W2t[(size_t)c * NHID + k] = f2bf(W2[i]);
  }
}

// ---- fused MLP: x -> relu(xW1+b1) -> (.)W2+b2 -> x0bf, g0 ----
// gemm1 A: register prefetch ring (depth 3) from global x, no LDS/barriers.
// h1 tile bounced via XOR-swizzled LDS; gemm2 in-kernel; packed epilogue.
__global__ __launch_bounds__(256) void mlp_k(const float* __restrict__ x,
                                             const short* __restrict__ W1t,
                                             const float* __restrict__ b1,
                                             const short* __restrict__ W2t,
                                             const float* __restrict__ b2,
                                             const float* __restrict__ dinv,
                                             unsigned short* __restrict__ x0,
                                             unsigned short* __restrict__ g0) {
  __shared__ __align__(16) short hs[64 * 128];    // 16KB h1 tile, XOR-swizzled rows of 256B
  __shared__ __align__(16) short ob[2][64 * 64];  // 2 x 8KB out bounce (x0, g0), rows of 128B
  int tid = threadIdx.x, lane = tid & 63, wave = tid >> 6;
  int r = lane & 15, q = lane >> 4;
  int rbase = blockIdx.x * 64 + wave * 16;
  int arow = rbase + r;
  int crow = arow < NNODES ? arow : NNODES - 1;
  const float* xr = x + (size_t)crow * NFEAT + q * 8;
  const short* bp1 = W1t + (size_t)r * NFEAT + q * 8;

  f4v acc[8];
#pragma unroll
  for (int i = 0; i < 8; ++i) acc[i] = (f4v){0.f, 0.f, 0.f, 0.f};

  // ---- gemm1 K-loop: 16 chunks of 32, A ring depth 3 ----
  float4 pa[4][2];
#pragma unroll
  for (int c = 0; c < 3; ++c) {
    pa[c][0] = *reinterpret_cast<const float4*>(xr + c * 32);
    pa[c][1] = *reinterpret_cast<const float4*>(xr + c * 32 + 4);
  }
#pragma unroll
  for (int c = 0; c < 16; ++c) {
    if (c + 3 < 16) {
      pa[(c + 3) & 3][0] = *reinterpret_cast<const float4*>(xr + (c + 3) * 32);
      pa[(c + 3) & 3][1] = *reinterpret_cast<const float4*>(xr + (c + 3) * 32 + 4);
    }
    float4 a0 = pa[c & 3][0], a1 = pa[c & 3][1];
    s8v a;
    a[0] = f2bf(a0.x); a[1] = f2bf(a0.y); a[2] = f2bf(a0.z); a[3] = f2bf(a0.w);
    a[4] = f2bf(a1.x); a[5] = f2bf(a1.y); a[6] = f2bf(a1.z); a[7] = f2bf(a1.w);
    const short* bk = bp1 + c * 32;
#pragma unroll
    for (int ct = 0; ct < 8; ++ct) {
      s8v b = *reinterpret_cast<const s8v*>(bk + (size_t)ct * 16 * NFEAT);
      acc[ct] = __builtin_amdgcn_mfma_f32_16x16x32_bf16(a, b, acc[ct], 0, 0, 0);
    }
  }

  // ---- h1 tile (relu, bf16) -> LDS, XOR-swizzled ----
  char* hsb = (char*)hs;
#pragma unroll
  for (int ct = 0; ct < 8; ++ct) {
    float bias = b1[ct * 16 + r];
#pragma unroll
    for (int j = 0; j < 4; ++j) {
      int row = q * 4 + j; // wave-local 0..15
      float v = acc[ct][j] + bias;
      v = v > 0.f ? v : 0.f;
      int byte = (ct * 32 + 2 * r) ^ ((row & 7) << 4);
      *(short*)(hsb + (wave * 16 + row) * 256 + byte) = f2bf(v);
    }
  }

  // ---- gemm2: h1_tile[16x128] @ W2 -> acc2[16x64] (same-wave LDS, no barrier) ----
  const short* bp2 = W2t + (size_t)r * NHID + q * 8;
  f4v acc2[4];
#pragma unroll
  for (int i = 0; i < 4; ++i) acc2[i] = (f4v){0.f, 0.f, 0.f, 0.f};
#pragma unroll
  for (int s = 0; s < 4; ++s) {
    int rb = (wave * 16 + r) * 256 + ((q * 16 + s * 64) ^ ((r & 7) << 4));
    s8v a = *reinterpret_cast<const s8v*>(hsb + rb);
#pragma unroll
    for (int ct = 0; ct < 4; ++ct) {
      s8v b = *reinterpret_cast<const s8v*>(bp2 + (size_t)ct * 16 * NHID + s * 32);
      acc2[ct] = __builtin_amdgcn_mfma_f32_16x16x32_bf16(a, b, acc2[ct], 0, 0, 0);
    }
  }

  // ---- epilogue: bias, dinv-scale, pack via LDS bounce, coalesced stores ----
  float dv[4];
#pragma unroll
  for (int j = 0; j < 4; ++j) {
    int grow = rbase + q * 4 + j;
    dv[j] = dinv[grow < NNODES ? grow : NNODES - 1];
  }
  char* ob0 = (char*)&ob[0][0];
  char* ob1 = (char*)&ob[1][0];
#pragma unroll
  for (int ct = 0; ct < 4; ++ct) {
    float bias = b2[ct * 16 + r];
#pragma unroll
    for (int j = 0; j < 4; ++j) {
      int row = q * 4 + j;
      float h = acc2[ct][j] + bias;
      int byte = (ct * 32 + 2 * r) ^ ((row & 7) << 4);
      int off = (wave * 16 + row) * 128 + byte;
      *(short*)(ob0 + off) = f2bf(h);
      *(short*)(ob1 + off) = f2bf(dv[j] * h);
    }
  }
  int orow = lane >> 2, opart = lane & 3;
  int c2 = (orow & 7) << 4;
  int rowoff = (wave * 16 + orow) * 128;
  int grow = rbase + orow;
  if (grow < NNODES) {
    s8v vx0a = *(const s8v*)(ob0 + rowoff + ((opart * 32) ^ c2));
    s8v vx0b = *(const s8v*)(ob0 + rowoff + ((opart * 32 + 16) ^ c2));
    s8v vg0a = *(const s8v*)(ob1 + rowoff + ((opart * 32) ^ c2));
    s8v vg0b = *(const s8v*)(ob1 + rowoff + ((opart * 32 + 16) ^ c2));
    *(s8v*)(x0 + (size_t)grow * NCLS + opart * 16) = vx0a;
    *(s8v*)(x0 + (size_t)grow * NCLS + opart * 16 + 8) = vx0b;
    *(s8v*)(g0 + (size_t)grow * NCLS + opart * 16) = vg0a;
    *(s8v*)(g0 + (size_t)grow * NCLS + opart * 16 + 8) = vg0b;
  }
}

// ---- propagation: 4 nodes/wave, 16 lanes/node, 4 classes/lane (uint2) ----
__global__ __launch_bounds__(256) void prop_k(const unsigned short* __restrict__ gin,
                                              const unsigned short* __restrict__ x0,
                                              const float* __restrict__ dinv,
                                              const int* __restrict__ rs,
                                              const int* __restrict__ csrc,
                                              unsigned short* __restrict__ gout,
                                              float* __restrict__ out,
                                              int last) {
  int tid = threadIdx.x;
  int lane = tid & 63;
  int r = lane & 15;
  int gbase = lane & 48;
  int node = blockIdx.x * 16 + (tid >> 6) * 4 + (lane >> 4);
  if (node >= NNODES) node = NNODES - 1;
  int b = rs[node];
  int deg = rs[node + 1] - b;

  // self contribution
  uint2 sv = ((const uint2*)(gin + (size_t)node * NCLS))[r];
  float a0 = bflo(sv.x), a1 = bfhi(sv.x), a2 = bflo(sv.y), a3 = bfhi(sv.y);

  // wave-uniform max degree over the 4 groups
  int m = deg;
  m = max(m, __shfl_xor(m, 16));
  m = max(m, __shfl_xor(m, 32));

  int basek = 0;
  for (; basek + 16 <= m; basek += 16) {
    int idx = NNODES;
    if (basek + r < deg) idx = csrc[b + basek + r];
#pragma unroll
    for (int j = 0; j < 16; ++j) {
      int sj = __shfl(idx, gbase + j);
      uint2 v = ((const uint2*)(gin + (size_t)sj * NCLS))[r];
      a0 += bflo(v.x); a1 += bfhi(v.x); a2 += bflo(v.y); a3 += bfhi(v.y);
    }
  }
  if (basek < m) {
    int idx = NNODES;
    if (basek + r < deg) idx = csrc[b + basek + r];
    int rem = m - basek;
    for (int j = 0; j < rem; ++j) {
      int sj = __shfl(idx, gbase + j);
      uint2 v = ((const uint2*)(gin + (size_t)sj * NCLS))[r];
      a0 += bflo(v.x); a1 += bfhi(v.x); a2 += bflo(v.y); a3 += bfhi(v.y);
    }
  }

  float dvn = dinv[node];
  uint2 xv = ((const uint2*)(x0 + (size_t)node * NCLS))[r];
  float h0 = 0.9f * (dvn * a0) + 0.1f * bflo(xv.x);
  float h1 = 0.9f * (dvn * a1) + 0.1f * bfhi(xv.x);
  float h2 = 0.9f * (dvn * a2) + 0.1f * bflo(xv.y);
  float h3 = 0.9f * (dvn * a3) + 0.1f * bfhi(xv.y);

  if (!last) {
    unsigned int p0 = (unsigned short)f2bf(dvn * h0) |
                      ((unsigned int)(unsigned short)f2bf(dvn * h1) << 16);
    unsigned int p1 = (unsigned short)f2bf(dvn * h2) |
                      ((unsigned int)(unsigned short)f2bf(dvn * h3) << 16);
    uint2 o; o.x = p0; o.y = p1;
    ((uint2*)(gout + (size_t)node * NCLS))[r] = o;
  } else {
    float mx = fmaxf(fmaxf(h0, h1), fmaxf(h2, h3));
#pragma unroll
    for (int off = 1; off < 16; off <<= 1) mx = fmaxf(mx, __shfl_xor(mx, off));
    float s = __expf(h0 - mx) + __expf(h1 - mx) + __expf(h2 - mx) + __expf(h3 - mx);
#pragma unroll
    for (int off = 1; off < 16; off <<= 1) s += __shfl_xor(s, off);
    float ls = __logf(s);
    float4 o = {h0 - mx - ls, h1 - mx - ls, h2 - mx - ls, h3 - mx - ls};
    *(float4*)(out + (size_t)node * NCLS + r * 4) = o;
  }
}

extern "C" void kernel_launch(void* const* d_in, const int* in_sizes, int n_in,
                              void* d_out, int out_size, void* d_ws, size_t ws_size,
                              hipStream_t stream) {
  const float* x  = (const float*)d_in[0];
  const int*   ei = (const int*)d_in[1];
  const float* W1 = (const float*)d_in[2];
  const float* b1 = (const float*)d_in[3];
  const float* W2 = (const float*)d_in[4];
  const float* b2 = (const float*)d_in[5];

  char* ws = (char*)d_ws;
  unsigned short* x0bf   = (unsigned short*)(ws);             // 12.8 MB
  unsigned short* gA     = (unsigned short*)(ws + 12800000);  // 12.8 MB + 128B zero row
  unsigned short* gB     = (unsigned short*)(ws + 25600128);  // 12.8 MB + 128B zero row
  int*            csrc   = (int*)(ws + 38400256);             // 6.4 MB
  int*            cnt    = (int*)(ws + 44800256);             // 400 KB
  int*            rs     = (int*)(ws + 45200256);             // 400.004 KB
  int*            cursor = (int*)(ws + 45600384);             // 400 KB
  float*          dinv   = (float*)(ws + 46000384);           // 400 KB
  short*          W1t    = (short*)(ws + 46400384);           // 131072 B
  short*          W2t    = (short*)(ws + 46531456);           // 16384 B
  int*            flag   = (int*)(ws + 46547840);             // 4 B
  int*            bsum   = (int*)(ws + 46547968);             // 1564 B

  hipMemsetAsync(ws + 44800256, 0, 1200128, stream); // cnt + rs + cursor
  hipMemsetAsync(ws + 46547840, 0, 4, stream);       // flag
  // zero null-gather row (index NNODES) in both state buffers
  hipMemsetAsync((char*)gA + (size_t)NNODES * NCLS * 2, 0, 128, stream);
  hipMemsetAsync((char*)gB + (size_t)NNODES * NCLS * 2, 0, 128, stream);

  detect_k<<<1, 1024, 0, stream>>>(ei, flag);
  hist_k<<<2048, 256, 0, stream>>>(ei, flag, cnt);
  scan1_k<<<NB1, 256, 0, stream>>>(cnt, rs, bsum);
  scan2_k<<<1, 512, 0, stream>>>(bsum, rs);
  scan3_k<<<NB1, 256, 0, stream>>>(cnt, bsum, rs, dinv);
  scatter_k<<<2048, 256, 0, stream>>>(ei, flag, rs, cursor, csrc);

  w1t_k<<<(NFEAT * NHID + 255) / 256, 256, 0, stream>>>(W1, W1t);
  w2t_k<<<(NHID * NCLS + 255) / 256, 256, 0, stream>>>(W2, W2t);

  mlp_k<<<(NNODES + 63) / 64, 256, 0, stream>>>(x, W1t, b1, W2t, b2, dinv, x0bf, gB);

  // g0 in gB; odd t writes gA, even t writes gB; t=10 reads gA, writes d_out (f32)
  for (int t = 1; t <= 10; ++t) {
    const unsigned short* gin = (t & 1) ? gB : gA;
    unsigned short* gout      = (t & 1) ? gA : gB;
    prop_k<<<(NNODES + 15) / 16, 256, 0, stream>>>(gin, x0bf, dinv, rs, csrc, gout,
                                                   (float*)d_out, t == 10);
  }
}